// Round 1
// baseline (213.215 us; speedup 1.0000x reference)
//
#include <hip/hip_runtime.h>

// Problem dims (fixed by reference setup_inputs)
#define NB   4
#define CIN  128
#define CS   32
#define HWS  1024          // H*W = 32*32
#define TT   32
#define CHUNK (HWS*TT)     // 32768 floats per (n, channel)
// ws float layout: [0,4096) qw1[32][128]; [4096,8192) qw2[128][32]; [8192,8320) msum[128]

__global__ __launch_bounds__(128) void wnorm_kernel(
    const float* __restrict__ v1, const float* __restrict__ g1,
    const float* __restrict__ v2, const float* __restrict__ g2,
    float* __restrict__ ws) {
  // blocks 0..31: rows of qw1 (len 128); blocks 32..159: rows of qw2 (len 32)
  int b = blockIdx.x, tid = threadIdx.x;
  bool first = (b < 32);
  int row = first ? b : b - 32;
  int len = first ? 128 : 32;
  const float* v = first ? v1 : v2;
  const float* g = first ? g1 : g2;
  float* qout = first ? ws : (ws + 4096);

  double val = 0.0;
  if (tid < len) { double t = (double)v[row * len + tid]; val = t * t; }
  for (int off = 32; off >= 1; off >>= 1) val += __shfl_down(val, off);
  __shared__ double partial[2];
  if ((tid & 63) == 0) partial[tid >> 6] = val;
  __syncthreads();
  double norm = sqrt(partial[0] + partial[1]);
  if (tid < len) {
    double w = (double)g[row] * (double)v[row * len + tid] / norm;
    double q = rint(w * 32.0) * 0.03125;       // round-half-even, step = 1/32? no: step=2/64=0.03125, 1/step=32
    q = fmin(fmax(q, -2.0), 1.984375);
    qout[row * len + tid] = (float)q;
  }
}

// msum[i] += sum over chunk of (T - t) * x  ; later scaled by 1/(N*HW*T)
__global__ __launch_bounds__(256) void mean_kernel(
    const float* __restrict__ x, float* __restrict__ msum) {
  int b = blockIdx.x, tid = threadIdx.x;
  int chunk = b >> 2, quarter = b & 3;      // chunk = n*128 + i
  int i = chunk & 127;
  const float4* xp = (const float4*)(x + (size_t)chunk * CHUNK + (size_t)quarter * 8192);
  float acc = 0.f;
#pragma unroll
  for (int it = 0; it < 8; ++it) {
    int f4i = tid + 256 * it;
    float4 v = xp[f4i];
    int t0 = (4 * f4i) & 31;
    acc += v.x * (float)(32 - t0) + v.y * (float)(31 - t0)
         + v.z * (float)(30 - t0) + v.w * (float)(29 - t0);
  }
  for (int off = 32; off >= 1; off >>= 1) acc += __shfl_down(acc, off);
  __shared__ float part[4];
  if ((tid & 63) == 0) part[tid >> 6] = acc;
  __syncthreads();
  if (tid == 0) atomicAdd(&msum[i], part[0] + part[1] + part[2] + part[3]);
}

__global__ __launch_bounds__(256) void fused_kernel(
    const float* __restrict__ x, const float* __restrict__ ws,
    float* __restrict__ out) {
  const float* qw1  = ws;            // [32][128]
  const float* qw2  = ws + 4096;     // [128][32]
  const float* msum = ws + 8192;     // [128]

  __shared__ float sxm[128][33];     // stage-1 input; reused as a2[128][33]
  __shared__ float z1[32][33];

  int tid = threadIdx.x;
  int pos = blockIdx.x;              // n*1024 + hw
  int n = pos >> 10, hw = pos & 1023;
  const float* xb = x + (size_t)n * CIN * CHUNK + (size_t)hw * TT;

  // ---- load + cumsum + mean-shift: thread -> (channel i, t-half) ----
  int i = tid >> 1, half = tid & 1;
  const float* xc = xb + (size_t)i * CHUNK + half * 16;
  float4 f0 = ((const float4*)xc)[0];
  float4 f1 = ((const float4*)xc)[1];
  float4 f2 = ((const float4*)xc)[2];
  float4 f3 = ((const float4*)xc)[3];
  float vals[16] = {f0.x,f0.y,f0.z,f0.w, f1.x,f1.y,f1.z,f1.w,
                    f2.x,f2.y,f2.z,f2.w, f3.x,f3.y,f3.z,f3.w};
  float run = 0.f;
#pragma unroll
  for (int k = 0; k < 16; ++k) { run += vals[k]; vals[k] = run; }
  float prefix = __shfl_up(run, 1);         // pairs (2j,2j+1) are wave-aligned
  if (!half) prefix = 0.f;
  float m = msum[i] * (1.0f / 131072.0f);   // /(N*HW*T)
#pragma unroll
  for (int k = 0; k < 16; ++k) sxm[i][half * 16 + k] = vals[k] + prefix - m;
  __syncthreads();

  // ---- stage 1: z1[o1][t] = sum_i qw1[o1][i] * sxm[i][t] ----
  int t = tid & 31, og = tid >> 5;          // og in 0..7
  float acc1[4] = {0.f, 0.f, 0.f, 0.f};
  for (int c = 0; c < 128; ++c) {
    float sv = sxm[c][t];
#pragma unroll
    for (int k = 0; k < 4; ++k) acc1[k] += qw1[(og + 8 * k) * 128 + c] * sv;
  }
#pragma unroll
  for (int k = 0; k < 4; ++k) z1[og + 8 * k][t] = acc1[k];
  __syncthreads();   // stage-1 sxm reads done; z1 visible

  // ---- stage 2: a2[o2][t] = clip(sum_j qw2[o2][j] * z1[j][t]) ----
  float acc2[16];
#pragma unroll
  for (int k = 0; k < 16; ++k) acc2[k] = 0.f;
  for (int j = 0; j < 32; ++j) {
    float zv = z1[j][t];
#pragma unroll
    for (int k = 0; k < 16; ++k) acc2[k] += qw2[(og + 8 * k) * 32 + j] * zv;
  }
#pragma unroll
  for (int k = 0; k < 16; ++k) {
    float av = fminf(fmaxf(acc2[k], -6.0f), 6.0f);
    sxm[og + 8 * k][t] = av;               // a2
  }
  __syncthreads();

  // ---- diff over t + coalesced writeout: thread -> (o2 = i, half) ----
  float prev = half ? sxm[i][15] : 0.0f;
  float dv[16];
#pragma unroll
  for (int k = 0; k < 16; ++k) {
    float cur = sxm[i][half * 16 + k];
    dv[k] = cur - prev;
    prev = cur;
  }
  float* ob = out + (size_t)n * CIN * CHUNK + (size_t)i * CHUNK + (size_t)hw * TT + half * 16;
  ((float4*)ob)[0] = make_float4(dv[0], dv[1], dv[2], dv[3]);
  ((float4*)ob)[1] = make_float4(dv[4], dv[5], dv[6], dv[7]);
  ((float4*)ob)[2] = make_float4(dv[8], dv[9], dv[10], dv[11]);
  ((float4*)ob)[3] = make_float4(dv[12], dv[13], dv[14], dv[15]);
}

extern "C" void kernel_launch(void* const* d_in, const int* in_sizes, int n_in,
                              void* d_out, int out_size, void* d_ws, size_t ws_size,
                              hipStream_t stream) {
  const float* x  = (const float*)d_in[0];
  const float* v1 = (const float*)d_in[1];
  const float* g1 = (const float*)d_in[2];
  const float* v2 = (const float*)d_in[3];
  const float* g2 = (const float*)d_in[4];
  float* ws  = (float*)d_ws;
  float* out = (float*)d_out;

  hipMemsetAsync(ws + 8192, 0, 128 * sizeof(float), stream);
  wnorm_kernel<<<160, 128, 0, stream>>>(v1, g1, v2, g2, ws);
  mean_kernel<<<2048, 256, 0, stream>>>(x, ws + 8192);
  fused_kernel<<<4096, 256, 0, stream>>>(x, ws, out);
}

// Round 2
// 64.604 us; speedup vs baseline: 3.3003x; 3.3003x over previous
//
#include <hip/hip_runtime.h>

// Problem dims (fixed by reference setup_inputs)
#define NB   4
#define CIN  128
#define CS   32
#define HWS  1024          // H*W
#define TT   32
#define CHUNKF 32768       // HW*T floats per (n, channel)
#define PPOS 8             // hw positions per block
// ws float layout: [0,4096) qw1[32][128]; [4096,8192) qw2[128][32]; [8192,8320) msum[128]

__global__ __launch_bounds__(128) void wnorm_kernel(
    const float* __restrict__ v1, const float* __restrict__ g1,
    const float* __restrict__ v2, const float* __restrict__ g2,
    float* __restrict__ ws) {
  int b = blockIdx.x, tid = threadIdx.x;
  bool first = (b < 32);
  int row = first ? b : b - 32;
  int len = first ? 128 : 32;
  const float* v = first ? v1 : v2;
  const float* g = first ? g1 : g2;
  float* qout = first ? ws : (ws + 4096);

  double val = 0.0;
  if (tid < len) { double t = (double)v[row * len + tid]; val = t * t; }
  for (int off = 32; off >= 1; off >>= 1) val += __shfl_down(val, off);
  __shared__ double partial[2];
  if ((tid & 63) == 0) partial[tid >> 6] = val;
  __syncthreads();
  double norm = sqrt(partial[0] + partial[1]);
  if (tid < len) {
    double w = (double)g[row] * (double)v[row * len + tid] / norm;
    double q = rint(w * 32.0) * 0.03125;       // step = 2/64
    q = fmin(fmax(q, -2.0), 1.984375);
    qout[row * len + tid] = (float)q;
  }
}

// msum[i] += sum over chunk of (T - t) * x   (scaled later by 1/(N*HW*T))
__global__ __launch_bounds__(256) void mean_kernel(
    const float* __restrict__ x, float* __restrict__ msum) {
  int b = blockIdx.x, tid = threadIdx.x;
  int chunk = b >> 2, quarter = b & 3;      // chunk = n*128 + i
  int i = chunk & 127;
  const float4* xp = (const float4*)(x + (size_t)chunk * CHUNKF + (size_t)quarter * 8192);
  float acc = 0.f;
#pragma unroll
  for (int it = 0; it < 8; ++it) {
    int f4i = tid + 256 * it;
    float4 v = xp[f4i];
    int t0 = (4 * f4i) & 31;
    acc += v.x * (float)(32 - t0) + v.y * (float)(31 - t0)
         + v.z * (float)(30 - t0) + v.w * (float)(29 - t0);
  }
  for (int off = 32; off >= 1; off >>= 1) acc += __shfl_down(acc, off);
  __shared__ float part[4];
  if ((tid & 63) == 0) part[tid >> 6] = acc;
  __syncthreads();
  if (tid == 0) atomicAdd(&msum[i], part[0] + part[1] + part[2] + part[3]);
}

// Fused: per block, P=8 contiguous hw positions; two-stage register-tiled GEMM.
// a2 = clip(qw2 * (qw1 * (cumsum_t x - mbar))), out = diff_t a2.
__global__ __launch_bounds__(256) void fused_kernel(
    const float* __restrict__ x, const float* __restrict__ ws,
    float* __restrict__ out) {
  const float* qw1  = ws;          // [32][128]
  const float* qw2  = ws + 4096;   // [128][32]
  const float* msum = ws + 8192;   // [128]

  // LDS layout (floats): w2T [32][132] @0 ; w1T [128][36] @4224 ;
  // st [8][8][36] @8832 ; z1 [32][8][36] overlays w1T+st @4224. Total 53760 B.
  __shared__ __align__(16) float smem[13440];
  float* w2T = smem;               // j*132 + o2
  float* w1T = smem + 4224;        // c*36 + o1
  float* st  = smem + 8832;        // (cl*8+p)*36 + t
  float* z1  = smem + 4224;        // (o1*8+p)*36 + t

  const int tid = threadIdx.x;
  const int og = tid >> 5;         // 0..7
  const int p  = (tid >> 2) & 7;   // 0..7 (position within tile)
  const int q  = tid & 3;          // 0..3 (t-run = 8q..8q+7)

  // weight preload (covered by first __syncthreads below)
#pragma unroll
  for (int k = 0; k < 16; ++k) {
    int idx = k * 256 + tid;
    w1T[(idx & 127) * 36 + (idx >> 7)] = qw1[idx];
  }
#pragma unroll
  for (int k = 0; k < 16; ++k) {
    int idx = k * 256 + tid;
    w2T[(idx & 31) * 132 + (idx >> 5)] = qw2[idx];
  }

  const int n   = blockIdx.x >> 7;
  const int hw0 = (blockIdx.x & 127) * PPOS;
  const float* xb = x + (size_t)n * CIN * CHUNKF + (size_t)hw0 * TT;

  float acc[4][8];
#pragma unroll
  for (int o = 0; o < 4; ++o)
#pragma unroll
    for (int t = 0; t < 8; ++t) acc[o][t] = 0.f;

  // ---- stage 1: z[o1] = sum_c qw1[o1][c] * (cumsum x[c] - m[c]), streamed in 8-ch chunks
  for (int ch = 0; ch < 16; ++ch) {
    const int cg = ch * 8 + og;                 // channel this thread stages
    const float* xc = xb + (size_t)cg * CHUNKF + p * TT + q * 8;
    float4 a0 = ((const float4*)xc)[0];
    float4 a1 = ((const float4*)xc)[1];
    float v[8] = {a0.x, a0.y, a0.z, a0.w, a1.x, a1.y, a1.z, a1.w};
    float run = 0.f;
#pragma unroll
    for (int k = 0; k < 8; ++k) { run += v[k]; v[k] = run; }
    float s1 = __shfl_up(run, 1);
    float s2 = __shfl_up(run, 2);
    float s3 = __shfl_up(run, 3);
    float pre = (q > 0 ? s1 : 0.f) + (q > 1 ? s2 : 0.f) + (q > 2 ? s3 : 0.f);
    const float m = msum[cg] * (1.0f / 131072.0f);
    float* srow = st + (og * 8 + p) * 36 + q * 8;
    ((float4*)srow)[0] = make_float4(v[0] + pre - m, v[1] + pre - m,
                                     v[2] + pre - m, v[3] + pre - m);
    ((float4*)srow)[1] = make_float4(v[4] + pre - m, v[5] + pre - m,
                                     v[6] + pre - m, v[7] + pre - m);
    __syncthreads();
#pragma unroll 4
    for (int cl = 0; cl < 8; ++cl) {
      float4 wv = *(const float4*)(w1T + (ch * 8 + cl) * 36 + og * 4);
      const float* sr = st + (cl * 8 + p) * 36 + q * 8;
      float4 sA = ((const float4*)sr)[0];
      float4 sB = ((const float4*)sr)[1];
      float sv[8] = {sA.x, sA.y, sA.z, sA.w, sB.x, sB.y, sB.z, sB.w};
      float wa[4] = {wv.x, wv.y, wv.z, wv.w};
#pragma unroll
      for (int o = 0; o < 4; ++o)
#pragma unroll
        for (int t = 0; t < 8; ++t) acc[o][t] += wa[o] * sv[t];
    }
    __syncthreads();
  }

  // ---- z1 to LDS (overlays w1T/st — all stage-1 reads completed above)
#pragma unroll
  for (int o = 0; o < 4; ++o) {
    float* zr = z1 + ((og * 4 + o) * 8 + p) * 36 + q * 8;
    ((float4*)zr)[0] = make_float4(acc[o][0], acc[o][1], acc[o][2], acc[o][3]);
    ((float4*)zr)[1] = make_float4(acc[o][4], acc[o][5], acc[o][6], acc[o][7]);
  }
  __syncthreads();

  // ---- stage 2: a2[o2] = clip(sum_j qw2[o2][j] * z1[j]); diff over t; store
  float* outb = out + (size_t)n * CIN * CHUNKF + (size_t)(hw0 + p) * TT + q * 8;
#pragma unroll
  for (int cc = 0; cc < 4; ++cc) {
    float a2[4][8];
#pragma unroll
    for (int o = 0; o < 4; ++o)
#pragma unroll
      for (int t = 0; t < 8; ++t) a2[o][t] = 0.f;
#pragma unroll 4
    for (int j = 0; j < 32; ++j) {
      float4 wv = *(const float4*)(w2T + j * 132 + og * 16 + cc * 4);
      const float* zr = z1 + (j * 8 + p) * 36 + q * 8;
      float4 zA = ((const float4*)zr)[0];
      float4 zB = ((const float4*)zr)[1];
      float zv[8] = {zA.x, zA.y, zA.z, zA.w, zB.x, zB.y, zB.z, zB.w};
      float wa[4] = {wv.x, wv.y, wv.z, wv.w};
#pragma unroll
      for (int o = 0; o < 4; ++o)
#pragma unroll
        for (int t = 0; t < 8; ++t) a2[o][t] += wa[o] * zv[t];
    }
#pragma unroll
    for (int o = 0; o < 4; ++o) {
      float a[8];
#pragma unroll
      for (int t = 0; t < 8; ++t) a[t] = fminf(fmaxf(a2[o][t], -6.0f), 6.0f);
      float plast = __shfl_up(a[7], 1);       // a[7] of q-1 lane (same og,p)
      float prev = (q == 0) ? 0.f : plast;
      float d[8];
#pragma unroll
      for (int t = 0; t < 8; ++t) { d[t] = a[t] - prev; prev = a[t]; }
      float* op = outb + (size_t)(og * 16 + cc * 4 + o) * CHUNKF;
      ((float4*)op)[0] = make_float4(d[0], d[1], d[2], d[3]);
      ((float4*)op)[1] = make_float4(d[4], d[5], d[6], d[7]);
    }
  }
}

extern "C" void kernel_launch(void* const* d_in, const int* in_sizes, int n_in,
                              void* d_out, int out_size, void* d_ws, size_t ws_size,
                              hipStream_t stream) {
  const float* x  = (const float*)d_in[0];
  const float* v1 = (const float*)d_in[1];
  const float* g1 = (const float*)d_in[2];
  const float* v2 = (const float*)d_in[3];
  const float* g2 = (const float*)d_in[4];
  float* ws  = (float*)d_ws;
  float* out = (float*)d_out;

  hipMemsetAsync(ws + 8192, 0, 128 * sizeof(float), stream);
  wnorm_kernel<<<160, 128, 0, stream>>>(v1, g1, v2, g2, ws);
  mean_kernel<<<2048, 256, 0, stream>>>(x, ws + 8192);
  fused_kernel<<<512, 256, 0, stream>>>(x, ws, out);
}